// Round 1
// baseline (403.787 us; speedup 1.0000x reference)
//
#include <hip/hip_runtime.h>

// y[n] = x[n] + ALPHA * y[n-1], zero init, per row. 64 rows x 960000 fp32.
// Chunked parallel scan: alpha^256 ~ 8.7e-19 => 256-sample warm-up lookback
// makes chunks independent to well below fp32 precision.

#define ALPHA 0.85f

constexpr int ROW    = 960000;
constexpr int T      = 16;           // elements per thread
constexpr int BT     = 256;          // threads per block
constexpr int TOT    = T * BT;       // 4096-element window
constexpr int LOOK   = 256;          // warm-up lookback (16 threads' worth)
constexpr int CHUNK  = TOT - LOOK;   // 3840 outputs per block
constexpr int CHUNKS = ROW / CHUNK;  // 250 (exact)

// alpha^n evaluated at compile time (double accumulate, cast to float).
constexpr float apow(int n) {
    double r = 1.0;
    for (int i = 0; i < n; ++i) r *= 0.85;
    return (float)r;
}

constexpr float A16   = apow(16);
constexpr float A32   = apow(32);
constexpr float A64   = apow(64);
constexpr float A128  = apow(128);
constexpr float A256  = apow(256);
constexpr float A512  = apow(512);
constexpr float A1024 = apow(1024);          // underflows to 0.0f — fine
constexpr float LOG2_A16 = -3.7514440648f;   // 16 * log2(0.85)

__global__ __launch_bounds__(BT) void deemph_kernel(const float* __restrict__ x,
                                                    float* __restrict__ y) {
    const int blk = blockIdx.x;
    const int r   = blk / CHUNKS;
    const int c   = blk - r * CHUNKS;
    const int t   = threadIdx.x;

    const long long rowbase = (long long)r * ROW;
    // window element 0 = chunk start - LOOK; thread t covers [t*T, t*T+T)
    const long long inbase = rowbase + (long long)c * CHUNK - LOOK + (long long)t * T;

    // ---- load 16 elements (float4 x4). Warm-up segs of chunk 0 are pre-row: zero.
    float v[T];
    if (c == 0 && t < LOOK / T) {
        #pragma unroll
        for (int i = 0; i < T; ++i) v[i] = 0.0f;
    } else {
        const float4* p = (const float4*)(x + inbase);
        #pragma unroll
        for (int i = 0; i < T / 4; ++i) {
            float4 q = p[i];
            v[4*i+0] = q.x; v[4*i+1] = q.y; v[4*i+2] = q.z; v[4*i+3] = q.w;
        }
    }

    // ---- local sequential scan (zero init): v[i] <- scan value, s = segment sum
    float s = 0.0f;
    #pragma unroll
    for (int i = 0; i < T; ++i) { s = v[i] + ALPHA * s; v[i] = s; }

    // ---- wave-level weighted Kogge-Stone inclusive scan of segment sums.
    // acc_t becomes state after lane t's segment assuming zero state at wave start.
    const int lane = t & 63;
    float acc = s;
    {
        float up;
        up = __shfl_up(acc, 1, 64);  if (lane >= 1)  acc += A16  * up;
        up = __shfl_up(acc, 2, 64);  if (lane >= 2)  acc += A32  * up;
        up = __shfl_up(acc, 4, 64);  if (lane >= 4)  acc += A64  * up;
        up = __shfl_up(acc, 8, 64);  if (lane >= 8)  acc += A128 * up;
        up = __shfl_up(acc, 16, 64); if (lane >= 16) acc += A256 * up;
        up = __shfl_up(acc, 32, 64); if (lane >= 32) acc += A512 * up;
    }

    // ---- cross-wave combine (4 waves)
    __shared__ float wsum[BT / 64];
    const int wave = t >> 6;
    if (lane == 63) wsum[wave] = acc;
    __syncthreads();
    float W = 0.0f;                          // state at start of this wave
    for (int w2 = 0; w2 < wave; ++w2) W = wsum[w2] + A1024 * W;

    // exclusive per-lane prefix within wave
    float excl = __shfl_up(acc, 1, 64);
    if (lane == 0) excl = 0.0f;
    // state just before this thread's segment: propagate W through `lane` segments
    const float P = excl + exp2f((float)lane * LOG2_A16) * W;

    // ---- apply prefix: y[i] = local[i] + alpha^{i+1} * P, store (non-warm-up only)
    if (t >= LOOK / T) {
        float m = ALPHA;
        float o[T];
        #pragma unroll
        for (int i = 0; i < T; ++i) { o[i] = v[i] + m * P; m *= ALPHA; }
        float4* q = (float4*)(y + inbase);
        #pragma unroll
        for (int i = 0; i < T / 4; ++i) {
            float4 w4 = { o[4*i+0], o[4*i+1], o[4*i+2], o[4*i+3] };
            q[i] = w4;
        }
    }
}

extern "C" void kernel_launch(void* const* d_in, const int* in_sizes, int n_in,
                              void* d_out, int out_size, void* d_ws, size_t ws_size,
                              hipStream_t stream) {
    const float* x = (const float*)d_in[0];
    float* y = (float*)d_out;
    const int nrows = in_sizes[0] / ROW;     // 64
    deemph_kernel<<<dim3(nrows * CHUNKS), dim3(BT), 0, stream>>>(x, y);
}